// Round 16
// baseline (169.226 us; speedup 1.0000x reference)
//
#include <hip/hip_runtime.h>

#define NEG_SLOPE 0.2f

typedef __attribute__((ext_vector_type(4))) float f32x4;
typedef __attribute__((ext_vector_type(2))) float f32x2;
typedef __attribute__((ext_vector_type(8))) short short8;

__device__ __forceinline__ f32x2 mk2(float a, float b) { f32x2 r; r[0] = a; r[1] = b; return r; }

__device__ __forceinline__ f32x2 FMA2(f32x2 a, f32x2 b, f32x2 c) {
#if __has_builtin(__builtin_elementwise_fma)
    return __builtin_elementwise_fma(a, b, c);
#else
    f32x2 r; r[0] = fmaf(a[0], b[0], c[0]); r[1] = fmaf(a[1], b[1], c[1]); return r;
#endif
}

__device__ __forceinline__ ushort f2bf(float f) {
    uint u = __float_as_uint(f);
    u += 0x7FFFu + ((u >> 16) & 1u);
    return (ushort)(u >> 16);
}
__device__ __forceinline__ float bflo(uint u) { return __uint_as_float(u << 16); }
__device__ __forceinline__ float bfhi(uint u) { return __uint_as_float(u & 0xffff0000u); }

// xpadA fragment-tiled layout: element (n,k) ->
//   nt=n>>6, g16=(n>>4)&3, r16=n&15, s=k>>5, kc=(k>>3)&3, j=k&7
//   ushort addr = ((nt*17+s)*4 + g16)*512 + (kc*16+r16)*8 + j
// BtT: (col,k) -> s=k>>5, cs=col>>4, fcol=col&15
//   ushort addr = (s*16+cs)*512 + (kc*16+fcol)*8 + j

// ---------------- conv pipe (conv2 via MFMA) + x->bf16 frag-tiled prep + fused degree count ----------------
__global__ __launch_bounds__(256) void k_conv_wave(
    const float* __restrict__ x, const float* __restrict__ onehot,
    const float* __restrict__ c1w, const float* __restrict__ c1b,
    const float* __restrict__ c2w, const float* __restrict__ c2b,
    const float* __restrict__ l2w, const float* __restrict__ l2b,
    ushort* __restrict__ xpadA, uint* __restrict__ ohb,
    const int* __restrict__ dstv, int* __restrict__ cursor, int N, int E) {
    __shared__ ushort Hall[4][1056];

    // fused degree count (cursor pre-zeroed by hipMemsetAsync); non-returning atomic -> no vmcnt dep
    const int gid = blockIdx.x * 256 + threadIdx.x;
    if (gid < E) atomicAdd(&cursor[dstv[gid]], 1);

    const int wave = threadIdx.x >> 6;
    const int lane = threadIdx.x & 63;
    const int n = blockIdx.x * 4 + wave;
    if (n >= N) return;
    ushort* H = Hall[wave];

    const int nt = n >> 6, g16 = (n >> 4) & 3, r16 = n & 15;
    const size_t qstep = ((size_t)nt*17)*4 + g16;

    // fused prepX: lane l holds k = l*8..l*8+7  ->  s=l>>2, kc=l&3
    {
        const float* xp = &x[(size_t)n*512 + lane*8];
        float4 lo = *reinterpret_cast<const float4*>(xp);
        float4 hi = *reinterpret_cast<const float4*>(xp + 4);
        uint4 w;
        w.x = (uint)f2bf(lo.x) | ((uint)f2bf(lo.y) << 16);
        w.y = (uint)f2bf(lo.z) | ((uint)f2bf(lo.w) << 16);
        w.z = (uint)f2bf(hi.x) | ((uint)f2bf(hi.y) << 16);
        w.w = (uint)f2bf(hi.z) | ((uint)f2bf(hi.w) << 16);
        const size_t a = (qstep + (size_t)(lane >> 2)*4)*512 + ((lane & 3)*16 + r16)*8;
        *reinterpret_cast<uint4*>(&xpadA[a]) = w;
    }

    float2 in2 = *reinterpret_cast<const float2*>(&onehot[(size_t)n * 128 + lane * 2]);
    ohb[(size_t)n*64 + lane] = (uint)f2bf(in2.x) | ((uint)f2bf(in2.y) << 16);
    float v0 = log1pf(in2.x);
    float v1 = log1pf(in2.y);

    // bitonic sort of 128 elements, fully in registers
    #pragma unroll
    for (int k = 2; k <= 128; k <<= 1) {
        const bool asc = ((lane & (k >> 1)) == 0);
        #pragma unroll
        for (int j = k >> 1; j >= 2; j >>= 1) {
            const int m = j >> 1;
            float p0 = __shfl_xor(v0, m, 64);
            float p1 = __shfl_xor(v1, m, 64);
            const bool keepmin = (((lane & m) == 0) == asc);
            v0 = keepmin ? fminf(v0, p0) : fmaxf(v0, p0);
            v1 = keepmin ? fminf(v1, p1) : fmaxf(v1, p1);
        }
        float lo = fminf(v0, v1), hi = fmaxf(v0, v1);
        v0 = asc ? lo : hi;
        v1 = asc ? hi : lo;
    }

    float pm = __shfl_up(v1, 1, 64); if (lane == 0)  pm = 0.f;
    float pp = __shfl_down(v0, 1, 64); if (lane == 63) pp = 0.f;

    float h0[8], h1[8];
    {
        const f32x2 xm = mk2(pm, v0), x0 = mk2(v0, v1), xp2 = mk2(v1, pp);
        #pragma unroll
        for (int c = 0; c < 8; ++c) {
            const float w0 = c1w[c*3+0], w1 = c1w[c*3+1], w2 = c1w[c*3+2], b = c1b[c];
            f32x2 h = FMA2(xm, mk2(w0, w0), FMA2(x0, mk2(w1, w1), FMA2(xp2, mk2(w2, w2), mk2(b, b))));
            h0[c] = fmaxf(h[0], 0.f);
            h1[c] = fmaxf(h[1], 0.f);
        }
    }

    // stage h (bf16) into LDS rows; zero boundary rows
    {
        if (lane == 0) {
            const uint4 z = make_uint4(0,0,0,0);
            *reinterpret_cast<uint4*>(&H[0*8])   = z;
            *reinterpret_cast<uint4*>(&H[130*8]) = z;
            *reinterpret_cast<uint4*>(&H[65*8])  = z;
        }
        uint4 w0, w1;
        w0.x = (uint)f2bf(h0[0]) | ((uint)f2bf(h0[1]) << 16);
        w0.y = (uint)f2bf(h0[2]) | ((uint)f2bf(h0[3]) << 16);
        w0.z = (uint)f2bf(h0[4]) | ((uint)f2bf(h0[5]) << 16);
        w0.w = (uint)f2bf(h0[6]) | ((uint)f2bf(h0[7]) << 16);
        w1.x = (uint)f2bf(h1[0]) | ((uint)f2bf(h1[1]) << 16);
        w1.y = (uint)f2bf(h1[2]) | ((uint)f2bf(h1[3]) << 16);
        w1.z = (uint)f2bf(h1[4]) | ((uint)f2bf(h1[5]) << 16);
        w1.w = (uint)f2bf(h1[6]) | ((uint)f2bf(h1[7]) << 16);
        *reinterpret_cast<uint4*>(&H[(66 + lane)*8]) = w0;
        *reinterpret_cast<uint4*>(&H[(lane + 1)*8])  = w1;
    }

    // conv2 as MFMA
    const int co = lane & 15;
    const int g2 = lane >> 4;
    short8 bfrag;
    #pragma unroll
    for (int j = 0; j < 8; ++j) bfrag[j] = 0;
    if (g2 < 3) {
        #pragma unroll
        for (int j = 0; j < 8; ++j) bfrag[j] = (short)f2bf(c2w[(co*8 + j)*3 + g2]);
    }
    const float bias_c = c2b[co];
    const f32x4 zacc = (f32x4)0.f;

    float poolv = 0.f;
    #pragma unroll
    for (int s = 0; s < 8; ++s) {
        const int qq = s*16 + co + g2;
        const int slot = (qq >> 1) + (qq & 1)*66;
        short8 afrag = *reinterpret_cast<const short8*>(&H[slot*8]);
        f32x4 d = __builtin_amdgcn_mfma_f32_16x16x32_bf16(afrag, bfrag, zacc, 0, 0, 0);
        poolv += fmaxf(d[0] + bias_c, 0.f);
        poolv += fmaxf(d[1] + bias_c, 0.f);
        poolv += fmaxf(d[2] + bias_c, 0.f);
        poolv += fmaxf(d[3] + bias_c, 0.f);
    }
    poolv += __shfl_xor(poolv, 16, 64);
    poolv += __shfl_xor(poolv, 32, 64);

    // linear 16 -> 8
    float rout = (lane < 8) ? l2b[lane] : 0.f;
    #pragma unroll
    for (int c = 0; c < 16; ++c) {
        float pc = __shfl(poolv, c, 64);
        if (lane < 8) rout = fmaf(pc * (1.f/128.f), l2w[c*8 + lane], rout);
    }
    // write readout (k 512..519 -> s=16, kc=0) + zero pad (kc 1..3)
    {
        const size_t qb = (qstep + 16u*4u)*512;
        if (lane < 4) {
            const int i0 = 2*lane, i1 = 2*lane + 1;
            float lo = __shfl(rout, i0, 64);
            float hi = __shfl(rout, i1, 64);
            uint w = (uint)f2bf(lo) | ((uint)f2bf(hi) << 16);
            *reinterpret_cast<uint*>(&xpadA[qb + r16*8 + lane*2]) = w;
        } else if (lane < 7) {
            const int kc = lane - 3;
            const uint4 z = make_uint4(0,0,0,0);
            *reinterpret_cast<uint4*>(&xpadA[qb + (kc*16 + r16)*8]) = z;
        }
    }
}

// ---------------- lin_w -> BtT (frag-tiled) ----------------
__global__ __launch_bounds__(256) void k_prepB(
    const float* __restrict__ lin_w, ushort* __restrict__ BtT) {
    const int col = blockIdx.x;
    const int cs = col >> 4, fcol = col & 15;
    for (int k = threadIdx.x; k < 544; k += 256) {
        float v = (k < 520) ? lin_w[(size_t)k*256 + col] : 0.f;
        const int s = k >> 5, kc = (k >> 3) & 3, j = k & 7;
        BtT[(size_t)(s*16 + cs)*512 + (kc*16 + fcol)*8 + j] = f2bf(v);
    }
}

// ---------------- single-pass block scan ----------------
__global__ __launch_bounds__(1024) void k_scan(int* __restrict__ deg, int* __restrict__ row_start, int N) {
    __shared__ int wsum[16];
    const int t = threadIdx.x;
    const int w = t >> 6, ln = t & 63;
    const int base = t * 20;
    int v[20];
    int run = 0;
    #pragma unroll
    for (int i = 0; i < 20; ++i) {
        const int idx = base + i;
        int d = 0;
        if (idx < N) { d = deg[idx]; deg[idx] = 0; }
        run += d;
        v[i] = run;
    }
    int s = run;
    #pragma unroll
    for (int d = 1; d < 64; d <<= 1) {
        int u = __shfl_up(s, d, 64);
        if (ln >= d) s += u;
    }
    if (ln == 63) wsum[w] = s;
    __syncthreads();
    if (w == 0) {
        int ws = (ln < 16) ? wsum[ln] : 0;
        int e2 = ws;
        #pragma unroll
        for (int d = 1; d < 16; d <<= 1) {
            int u = __shfl_up(e2, d, 64);
            if (ln >= d) e2 += u;
        }
        if (ln < 16) wsum[ln] = e2 - ws;
    }
    __syncthreads();
    const int off = (s - run) + wsum[w];
    if (t == 0) row_start[0] = 0;
    #pragma unroll
    for (int i = 0; i < 20; ++i) {
        const int idx = base + i;
        if (idx < N) row_start[idx + 1] = off + v[i];
    }
}

// ---------------- bf16-MFMA GEMM, 32x32 tile, 2 waves, 4-buffer/distance-3 pipeline ----------------
// wave wv covers rows [m0+wv*16, +16), both 16-col subtiles of the 32-col chunk.
__global__ __launch_bounds__(128, 6) void k_gemm_mfma(
    const ushort* __restrict__ xpadA, const ushort* __restrict__ BtT,
    const float* __restrict__ att_l, const float* __restrict__ att_r,
    ushort* __restrict__ xhb, float* __restrict__ al, float* __restrict__ ar,
    const int* __restrict__ src, const int* __restrict__ dstv,
    const int* __restrict__ row_start, int* __restrict__ cursor, int* __restrict__ csr,
    int N, int E) {
    __shared__ __align__(16) float ep[32*36];

    const int t = threadIdx.x;
    const int wv = t >> 6, lane = t & 63;

    // bijective XCD swizzle (m204)
    const int nwg = gridDim.x;
    const int q = nwg >> 3, r = nwg & 7;
    const int xcd = blockIdx.x & 7, idx = blockIdx.x >> 3;
    const int logical = (xcd < r ? xcd*(q+1) : r*(q+1) + (xcd-r)*q) + idx;
    const int lt = logical >> 3;          // 32-row tile index
    const int ch = logical & 7;           // 32-col chunk (= head)
    const int m0 = lt * 32;
    const int c0 = ch * 32;
    const int cs = ch * 2;

    const int nt = lt >> 1;
    const int gbase = (lt & 1) * 2 + wv;  // 16-row quarter within the 64-row supertile

    const ushort* A0 = xpadA + ((size_t)(nt*17)*4 + gbase)*512 + lane*8;
    const ushort* B0 = BtT + (size_t)(cs + 0)*512 + lane*8;
    const ushort* B1 = BtT + (size_t)(cs + 1)*512 + lane*8;

    f32x4 acc0 = (f32x4)0.f, acc1 = (f32x4)0.f;

    // 4 buffers, prefetch distance 3 (R15 bug: distance == buffer count aliases the live buffer)
    short8 a[4], b0[4], b1[4];
#define LOADSET(B_, S_)                                                       \
    {                                                                         \
        a[B_]  = *reinterpret_cast<const short8*>(A0 + (size_t)(S_)*2048);    \
        b0[B_] = *reinterpret_cast<const short8*>(B0 + (size_t)(S_)*8192);    \
        b1[B_] = *reinterpret_cast<const short8*>(B1 + (size_t)(S_)*8192);    \
    }
    LOADSET(0, 0)
    LOADSET(1, 1)
    LOADSET(2, 2)
    #pragma unroll
    for (int s = 0; s < 17; ++s) {
        const int b = s & 3;
        if (s + 3 < 17) LOADSET((s + 3) & 3, s + 3)
        acc0 = __builtin_amdgcn_mfma_f32_16x16x32_bf16(a[b], b0[b], acc0, 0, 0, 0);
        acc1 = __builtin_amdgcn_mfma_f32_16x16x32_bf16(a[b], b1[b], acc1, 0, 0, 0);
    }
#undef LOADSET

    // fused CSR fill — after the K-loop (R11 lesson: vmcnt waits are oldest-first)
    {
        const int e = blockIdx.x * 128 + t;
        if (e < E) {
            const int d = dstv[e];
            const int p = atomicAdd(&cursor[d], 1);
            csr[row_start[d] + p] = src[e];
        }
    }

    // ---- epilogue: transpose through LDS; emit bf16 rows + al/ar (block = 1 head) ----
    {
        const int rq = (lane >> 4) * 4;
        const int cb = lane & 15;
        #pragma unroll
        for (int r2 = 0; r2 < 4; ++r2) {
            ep[(wv*16 + rq + r2)*36 +      cb] = acc0[r2];
            ep[(wv*16 + rq + r2)*36 + 16 + cb] = acc1[r2];
        }
    }
    __syncthreads();
    {
        const int rl = t >> 2;           // 32 rows, 4 threads/row
        const int cq = (t & 3) * 8;      // 8 cols each
        const int row = m0 + rl;
        if (row < N) {
            const float* sp = &ep[rl*36 + cq];
            float vals[8];
            #pragma unroll
            for (int i = 0; i < 8; ++i) vals[i] = sp[i];
            uint u[4];
            #pragma unroll
            for (int i = 0; i < 4; ++i)
                u[i] = (uint)f2bf(vals[2*i]) | ((uint)f2bf(vals[2*i+1]) << 16);
            *reinterpret_cast<uint4*>(&xhb[(size_t)row*256 + c0 + cq]) = make_uint4(u[0], u[1], u[2], u[3]);
            float pl = 0.f, pr = 0.f;
            #pragma unroll
            for (int i = 0; i < 8; ++i) {
                pl = fmaf(vals[i], att_l[c0 + cq + i], pl);
                pr = fmaf(vals[i], att_r[c0 + cq + i], pr);
            }
            pl += __shfl_xor(pl, 1, 64);
            pr += __shfl_xor(pr, 1, 64);
            pl += __shfl_xor(pl, 2, 64);
            pr += __shfl_xor(pr, 2, 64);
            if ((t & 3) == 0) {
                al[(size_t)row*8 + ch] = pl;
                ar[(size_t)row*8 + ch] = pr;
            }
        }
    }
}

// ---------------- per-dst single-pass softmax aggregation: 2 nodes/wave, 32 lanes/node ----------------
__global__ __launch_bounds__(256) void k_agg(
    const ushort* __restrict__ xhb,
    const float* __restrict__ al, const float* __restrict__ ar,
    const float* __restrict__ onehot, const uint* __restrict__ ohb,
    const float* __restrict__ bias,
    const int* __restrict__ row_start, const int* __restrict__ csr,
    float* __restrict__ out_x, float* __restrict__ out_oh, int N) {
    const int wave = threadIdx.x >> 6;
    const int lane = threadIdx.x & 63;
    const int half = lane >> 5;
    const int ln = lane & 31;
    const int n = blockIdx.x * 8 + wave * 2 + half;
    if (n >= N) return;
    const int h = ln >> 2;
    const float ard = ar[(size_t)n*8 + h];

    float a_self = al[(size_t)n*8 + h] + ard;
    a_self = fmaxf(a_self, NEG_SLOPE * a_self);
    float e_self = __expf(a_self);
    uint4 xsb = *reinterpret_cast<const uint4*>(&xhb[(size_t)n*256 + ln*8]);
    float acc0 = e_self * bflo(xsb.x), acc1 = e_self * bfhi(xsb.x);
    float acc2 = e_self * bflo(xsb.y), acc3 = e_self * bfhi(xsb.y);
    float acc4 = e_self * bflo(xsb.z), acc5 = e_self * bfhi(xsb.z);
    float acc6 = e_self * bflo(xsb.w), acc7 = e_self * bfhi(xsb.w);
    float den = e_self;
    float oh0 = 0.f, oh1 = 0.f, oh2 = 0.f, oh3 = 0.f;

    const int beg = row_start[n], end = row_start[n+1];
    int i = beg;
    for (; i + 1 < end; i += 2) {
        const int s0 = csr[i], s1 = csr[i+1];
        const float al0 = al[(size_t)s0*8 + h], al1 = al[(size_t)s1*8 + h];
        const uint4 x0 = *reinterpret_cast<const uint4*>(&xhb[(size_t)s0*256 + ln*8]);
        const uint4 x1 = *reinterpret_cast<const uint4*>(&xhb[(size_t)s1*256 + ln*8]);
        const uint2 o0 = *reinterpret_cast<const uint2*>(&ohb[(size_t)s0*64 + ln*2]);
        const uint2 o1 = *reinterpret_cast<const uint2*>(&ohb[(size_t)s1*64 + ln*2]);
        float a0 = al0 + ard; a0 = fmaxf(a0, NEG_SLOPE * a0);
        float a1 = al1 + ard; a1 = fmaxf(a1, NEG_SLOPE * a1);
        const float e0 = __expf(a0), e1 = __expf(a1);
        acc0 = fmaf(e0, bflo(x0.x), fmaf(e1, bflo(x1.x), acc0));
        acc1 = fmaf(e0, bfhi(x0.x), fmaf(e1, bfhi(x1.x), acc1));
        acc2 = fmaf(e0, bflo(x0.y), fmaf(e1, bflo(x1.y), acc2));
        acc3 = fmaf(e0, bfhi(x0.y), fmaf(e1, bfhi(x1.y), acc3));
        acc4 = fmaf(e0, bflo(x0.z), fmaf(e1, bflo(x1.z), acc4));
        acc5 = fmaf(e0, bfhi(x0.z), fmaf(e1, bfhi(x1.z), acc5));
        acc6 = fmaf(e0, bflo(x0.w), fmaf(e1, bflo(x1.w), acc6));
        acc7 = fmaf(e0, bfhi(x0.w), fmaf(e1, bfhi(x1.w), acc7));
        den += e0 + e1;
        oh0 += bflo(o0.x) + bflo(o1.x);
        oh1 += bfhi(o0.x) + bfhi(o1.x);
        oh2 += bflo(o0.y) + bflo(o1.y);
        oh3 += bfhi(o0.y) + bfhi(o1.y);
    }
    if (i < end) {
        const int s0 = csr[i];
        float a0 = al[(size_t)s0*8 + h] + ard;
        a0 = fmaxf(a0, NEG_SLOPE * a0);
        const float e0 = __expf(a0);
        const uint4 x0 = *reinterpret_cast<const uint4*>(&xhb[(size_t)s0*256 + ln*8]);
        const uint2 o0 = *reinterpret_cast<const uint2*>(&ohb[(size_t)s0*64 + ln*2]);
        acc0 = fmaf(e0, bflo(x0.x), acc0);
        acc1 = fmaf(e0, bfhi(x0.x), acc1);
        acc2 = fmaf(e0, bflo(x0.y), acc2);
        acc3 = fmaf(e0, bfhi(x0.y), acc3);
        acc4 = fmaf(e0, bflo(x0.z), acc4);
        acc5 = fmaf(e0, bfhi(x0.z), acc5);
        acc6 = fmaf(e0, bflo(x0.w), acc6);
        acc7 = fmaf(e0, bfhi(x0.w), acc7);
        den += e0;
        oh0 += bflo(o0.x);
        oh1 += bfhi(o0.x);
        oh2 += bflo(o0.y);
        oh3 += bfhi(o0.y);
    }
    const float inv = 1.f / den;
    const float4 bv0 = *reinterpret_cast<const float4*>(&bias[ln*8]);
    const float4 bv1 = *reinterpret_cast<const float4*>(&bias[ln*8 + 4]);
    float4 q0, q1;
    q0.x = fmaf(acc0, inv, bv0.x); q0.y = fmaf(acc1, inv, bv0.y);
    q0.z = fmaf(acc2, inv, bv0.z); q0.w = fmaf(acc3, inv, bv0.w);
    q1.x = fmaf(acc4, inv, bv1.x); q1.y = fmaf(acc5, inv, bv1.y);
    q1.z = fmaf(acc6, inv, bv1.z); q1.w = fmaf(acc7, inv, bv1.w);
    *reinterpret_cast<float4*>(&out_x[(size_t)n*256 + ln*8])     = q0;
    *reinterpret_cast<float4*>(&out_x[(size_t)n*256 + ln*8 + 4]) = q1;
    const float4 so = *reinterpret_cast<const float4*>(&onehot[(size_t)n*128 + ln*4]);
    float4 oo;
    oo.x = oh0 + 2.f*so.x;
    oo.y = oh1 + 2.f*so.y;
    oo.z = oh2 + 2.f*so.z;
    oo.w = oh3 + 2.f*so.w;
    *reinterpret_cast<float4*>(&out_oh[(size_t)n*128 + ln*4]) = oo;
}

// ---------------- launcher ----------------
extern "C" void kernel_launch(void* const* d_in, const int* in_sizes, int n_in,
                              void* d_out, int out_size, void* d_ws, size_t ws_size,
                              hipStream_t stream) {
    const float* x      = (const float*)d_in[0];
    const float* onehot = (const float*)d_in[1];
    const int*   adj    = (const int*)d_in[2];
    const float* lin_w  = (const float*)d_in[4];
    const float* att_l  = (const float*)d_in[5];
    const float* att_r  = (const float*)d_in[6];
    const float* bias   = (const float*)d_in[7];
    const float* c1w    = (const float*)d_in[8];
    const float* c1b    = (const float*)d_in[9];
    const float* c2w    = (const float*)d_in[10];
    const float* c2b    = (const float*)d_in[11];
    const float* l2w    = (const float*)d_in[12];
    const float* l2b    = (const float*)d_in[13];

    const int N = in_sizes[0] / 512;
    const int E = in_sizes[2] / 2;
    const int* src = adj;
    const int* dst = adj + E;

    float* out_x  = (float*)d_out;
    float* out_oh = out_x + (size_t)N * 256;

    const int NT = (N + 63) / 64;

    // workspace layout
    ushort* xpadA    = (ushort*)d_ws;                       // NT*17*2048 ushorts (frag-tiled)
    ushort* BtT      = xpadA + (size_t)NT * 17 * 2048;      // 17*8192 ushorts
    ushort* xhb      = BtT + (size_t)17 * 8192;             // N*256 bf16
    uint*   ohb      = (uint*)(xhb + (size_t)N * 256);      // N*64 packed bf16x2
    float*  al       = (float*)(ohb + (size_t)N * 64);      // N*8
    float*  ar       = al + (size_t)N * 8;                  // N*8
    int*   row_start = (int*)(ar + (size_t)N * 8);          // N+1
    int*   cursor    = row_start + (N + 1);                 // N
    int*   csr       = cursor + N;                          // E

    const int NT32 = (N + 31) / 32;
    const int GB = NT32 * 8;

    hipMemsetAsync(cursor, 0, (size_t)N * sizeof(int), stream);
    k_conv_wave<<<(N + 3) / 4, 256, 0, stream>>>(x, onehot, c1w, c1b, c2w, c2b, l2w, l2b, xpadA, ohb, dst, cursor, N, E);
    k_prepB<<<256, 256, 0, stream>>>(lin_w, BtT);
    k_scan<<<1, 1024, 0, stream>>>(cursor, row_start, N);
    k_gemm_mfma<<<GB, 128, 0, stream>>>(xpadA, BtT, att_l, att_r, xhb, al, ar,
                                        src, dst, row_start, cursor, csr, N, E);
    k_agg<<<(N + 7) / 8, 256, 0, stream>>>(xhb, al, ar, onehot, ohb, bias, row_start, csr, out_x, out_oh, N);
}

// Round 17
// 163.556 us; speedup vs baseline: 1.0347x; 1.0347x over previous
//
#include <hip/hip_runtime.h>

#define NEG_SLOPE 0.2f

typedef __attribute__((ext_vector_type(4))) float f32x4;
typedef __attribute__((ext_vector_type(2))) float f32x2;
typedef __attribute__((ext_vector_type(8))) short short8;

__device__ __forceinline__ f32x2 mk2(float a, float b) { f32x2 r; r[0] = a; r[1] = b; return r; }

__device__ __forceinline__ f32x2 FMA2(f32x2 a, f32x2 b, f32x2 c) {
#if __has_builtin(__builtin_elementwise_fma)
    return __builtin_elementwise_fma(a, b, c);
#else
    f32x2 r; r[0] = fmaf(a[0], b[0], c[0]); r[1] = fmaf(a[1], b[1], c[1]); return r;
#endif
}

__device__ __forceinline__ ushort f2bf(float f) {
    uint u = __float_as_uint(f);
    u += 0x7FFFu + ((u >> 16) & 1u);
    return (ushort)(u >> 16);
}
__device__ __forceinline__ float bflo(uint u) { return __uint_as_float(u << 16); }
__device__ __forceinline__ float bfhi(uint u) { return __uint_as_float(u & 0xffff0000u); }

// xpadA fragment-tiled layout: element (n,k) ->
//   nt=n>>6, g16=(n>>4)&3, r16=n&15, s=k>>5, kc=(k>>3)&3, j=k&7
//   ushort addr = ((nt*17+s)*4 + g16)*512 + (kc*16+r16)*8 + j
// BtT: (col,k) -> s=k>>5, cs=col>>4, fcol=col&15
//   ushort addr = (s*16+cs)*512 + (kc*16+fcol)*8 + j

// ---------------- conv pipe (conv2 via MFMA) + x->bf16 frag-tiled prep + cursor zero ----------------
__global__ __launch_bounds__(256) void k_conv_wave(
    const float* __restrict__ x, const float* __restrict__ onehot,
    const float* __restrict__ c1w, const float* __restrict__ c1b,
    const float* __restrict__ c2w, const float* __restrict__ c2b,
    const float* __restrict__ l2w, const float* __restrict__ l2b,
    ushort* __restrict__ xpadA, uint* __restrict__ ohb, int* __restrict__ cursor, int N) {
    __shared__ ushort Hall[4][1056];

    // zero cursor (completes before k_prep's atomics via stream order)
    const int gid = blockIdx.x * 256 + threadIdx.x;
    if (gid < N) cursor[gid] = 0;

    const int wave = threadIdx.x >> 6;
    const int lane = threadIdx.x & 63;
    const int n = blockIdx.x * 4 + wave;
    if (n >= N) return;
    ushort* H = Hall[wave];

    const int nt = n >> 6, g16 = (n >> 4) & 3, r16 = n & 15;
    const size_t qstep = ((size_t)nt*17)*4 + g16;

    // fused prepX: lane l holds k = l*8..l*8+7  ->  s=l>>2, kc=l&3
    {
        const float* xp = &x[(size_t)n*512 + lane*8];
        float4 lo = *reinterpret_cast<const float4*>(xp);
        float4 hi = *reinterpret_cast<const float4*>(xp + 4);
        uint4 w;
        w.x = (uint)f2bf(lo.x) | ((uint)f2bf(lo.y) << 16);
        w.y = (uint)f2bf(lo.z) | ((uint)f2bf(lo.w) << 16);
        w.z = (uint)f2bf(hi.x) | ((uint)f2bf(hi.y) << 16);
        w.w = (uint)f2bf(hi.z) | ((uint)f2bf(hi.w) << 16);
        const size_t a = (qstep + (size_t)(lane >> 2)*4)*512 + ((lane & 3)*16 + r16)*8;
        *reinterpret_cast<uint4*>(&xpadA[a]) = w;
    }

    float2 in2 = *reinterpret_cast<const float2*>(&onehot[(size_t)n * 128 + lane * 2]);
    ohb[(size_t)n*64 + lane] = (uint)f2bf(in2.x) | ((uint)f2bf(in2.y) << 16);
    float v0 = log1pf(in2.x);
    float v1 = log1pf(in2.y);

    // bitonic sort of 128 elements, fully in registers
    #pragma unroll
    for (int k = 2; k <= 128; k <<= 1) {
        const bool asc = ((lane & (k >> 1)) == 0);
        #pragma unroll
        for (int j = k >> 1; j >= 2; j >>= 1) {
            const int m = j >> 1;
            float p0 = __shfl_xor(v0, m, 64);
            float p1 = __shfl_xor(v1, m, 64);
            const bool keepmin = (((lane & m) == 0) == asc);
            v0 = keepmin ? fminf(v0, p0) : fmaxf(v0, p0);
            v1 = keepmin ? fminf(v1, p1) : fmaxf(v1, p1);
        }
        float lo = fminf(v0, v1), hi = fmaxf(v0, v1);
        v0 = asc ? lo : hi;
        v1 = asc ? hi : lo;
    }

    float pm = __shfl_up(v1, 1, 64); if (lane == 0)  pm = 0.f;
    float pp = __shfl_down(v0, 1, 64); if (lane == 63) pp = 0.f;

    float h0[8], h1[8];
    {
        const f32x2 xm = mk2(pm, v0), x0 = mk2(v0, v1), xp2 = mk2(v1, pp);
        #pragma unroll
        for (int c = 0; c < 8; ++c) {
            const float w0 = c1w[c*3+0], w1 = c1w[c*3+1], w2 = c1w[c*3+2], b = c1b[c];
            f32x2 h = FMA2(xm, mk2(w0, w0), FMA2(x0, mk2(w1, w1), FMA2(xp2, mk2(w2, w2), mk2(b, b))));
            h0[c] = fmaxf(h[0], 0.f);
            h1[c] = fmaxf(h[1], 0.f);
        }
    }

    // stage h (bf16) into LDS rows; zero boundary rows
    {
        if (lane == 0) {
            const uint4 z = make_uint4(0,0,0,0);
            *reinterpret_cast<uint4*>(&H[0*8])   = z;
            *reinterpret_cast<uint4*>(&H[130*8]) = z;
            *reinterpret_cast<uint4*>(&H[65*8])  = z;
        }
        uint4 w0, w1;
        w0.x = (uint)f2bf(h0[0]) | ((uint)f2bf(h0[1]) << 16);
        w0.y = (uint)f2bf(h0[2]) | ((uint)f2bf(h0[3]) << 16);
        w0.z = (uint)f2bf(h0[4]) | ((uint)f2bf(h0[5]) << 16);
        w0.w = (uint)f2bf(h0[6]) | ((uint)f2bf(h0[7]) << 16);
        w1.x = (uint)f2bf(h1[0]) | ((uint)f2bf(h1[1]) << 16);
        w1.y = (uint)f2bf(h1[2]) | ((uint)f2bf(h1[3]) << 16);
        w1.z = (uint)f2bf(h1[4]) | ((uint)f2bf(h1[5]) << 16);
        w1.w = (uint)f2bf(h1[6]) | ((uint)f2bf(h1[7]) << 16);
        *reinterpret_cast<uint4*>(&H[(66 + lane)*8]) = w0;
        *reinterpret_cast<uint4*>(&H[(lane + 1)*8])  = w1;
    }

    // conv2 as MFMA
    const int co = lane & 15;
    const int g2 = lane >> 4;
    short8 bfrag;
    #pragma unroll
    for (int j = 0; j < 8; ++j) bfrag[j] = 0;
    if (g2 < 3) {
        #pragma unroll
        for (int j = 0; j < 8; ++j) bfrag[j] = (short)f2bf(c2w[(co*8 + j)*3 + g2]);
    }
    const float bias_c = c2b[co];
    const f32x4 zacc = (f32x4)0.f;

    float poolv = 0.f;
    #pragma unroll
    for (int s = 0; s < 8; ++s) {
        const int qq = s*16 + co + g2;
        const int slot = (qq >> 1) + (qq & 1)*66;
        short8 afrag = *reinterpret_cast<const short8*>(&H[slot*8]);
        f32x4 d = __builtin_amdgcn_mfma_f32_16x16x32_bf16(afrag, bfrag, zacc, 0, 0, 0);
        poolv += fmaxf(d[0] + bias_c, 0.f);
        poolv += fmaxf(d[1] + bias_c, 0.f);
        poolv += fmaxf(d[2] + bias_c, 0.f);
        poolv += fmaxf(d[3] + bias_c, 0.f);
    }
    poolv += __shfl_xor(poolv, 16, 64);
    poolv += __shfl_xor(poolv, 32, 64);

    // linear 16 -> 8
    float rout = (lane < 8) ? l2b[lane] : 0.f;
    #pragma unroll
    for (int c = 0; c < 16; ++c) {
        float pc = __shfl(poolv, c, 64);
        if (lane < 8) rout = fmaf(pc * (1.f/128.f), l2w[c*8 + lane], rout);
    }
    // write readout (k 512..519 -> s=16, kc=0) + zero pad (kc 1..3)
    {
        const size_t qb = (qstep + 16u*4u)*512;
        if (lane < 4) {
            const int i0 = 2*lane, i1 = 2*lane + 1;
            float lo = __shfl(rout, i0, 64);
            float hi = __shfl(rout, i1, 64);
            uint w = (uint)f2bf(lo) | ((uint)f2bf(hi) << 16);
            *reinterpret_cast<uint*>(&xpadA[qb + r16*8 + lane*2]) = w;
        } else if (lane < 7) {
            const int kc = lane - 3;
            const uint4 z = make_uint4(0,0,0,0);
            *reinterpret_cast<uint4*>(&xpadA[qb + (kc*16 + r16)*8]) = z;
        }
    }
}

// ---------------- fused: lin_w -> BtT (frag-tiled) + degree count ----------------
__global__ __launch_bounds__(256) void k_prep(
    const float* __restrict__ lin_w, ushort* __restrict__ BtT,
    const int* __restrict__ dstv, int* __restrict__ cursor, int E) {
    const int gid = blockIdx.x * 256 + threadIdx.x;
    if (gid < E) atomicAdd(&cursor[dstv[gid]], 1);
    const int col = blockIdx.x;
    if (col < 256) {
        const int cs = col >> 4, fcol = col & 15;
        for (int k = threadIdx.x; k < 544; k += 256) {
            float v = (k < 520) ? lin_w[(size_t)k*256 + col] : 0.f;
            const int s = k >> 5, kc = (k >> 3) & 3, j = k & 7;
            BtT[(size_t)(s*16 + cs)*512 + (kc*16 + fcol)*8 + j] = f2bf(v);
        }
    }
}

// ---------------- single-pass block scan ----------------
__global__ __launch_bounds__(1024) void k_scan(int* __restrict__ deg, int* __restrict__ row_start, int N) {
    __shared__ int wsum[16];
    const int t = threadIdx.x;
    const int w = t >> 6, ln = t & 63;
    const int base = t * 20;
    int v[20];
    int run = 0;
    #pragma unroll
    for (int i = 0; i < 20; ++i) {
        const int idx = base + i;
        int d = 0;
        if (idx < N) { d = deg[idx]; deg[idx] = 0; }
        run += d;
        v[i] = run;
    }
    int s = run;
    #pragma unroll
    for (int d = 1; d < 64; d <<= 1) {
        int u = __shfl_up(s, d, 64);
        if (ln >= d) s += u;
    }
    if (ln == 63) wsum[w] = s;
    __syncthreads();
    if (w == 0) {
        int ws = (ln < 16) ? wsum[ln] : 0;
        int e2 = ws;
        #pragma unroll
        for (int d = 1; d < 16; d <<= 1) {
            int u = __shfl_up(e2, d, 64);
            if (ln >= d) e2 += u;
        }
        if (ln < 16) wsum[ln] = e2 - ws;
    }
    __syncthreads();
    const int off = (s - run) + wsum[w];
    if (t == 0) row_start[0] = 0;
    #pragma unroll
    for (int i = 0; i < 20; ++i) {
        const int idx = base + i;
        if (idx < N) row_start[idx + 1] = off + v[i];
    }
}

// ---------------- bf16-MFMA GEMM, 32x32 tile, 2 waves, 4-buffer/distance-3 pipeline ----------------
__global__ __launch_bounds__(128, 6) void k_gemm_mfma(
    const ushort* __restrict__ xpadA, const ushort* __restrict__ BtT,
    const float* __restrict__ att_l, const float* __restrict__ att_r,
    ushort* __restrict__ xhb, float* __restrict__ al, float* __restrict__ ar,
    const int* __restrict__ src, const int* __restrict__ dstv,
    const int* __restrict__ row_start, int* __restrict__ cursor, int* __restrict__ csr,
    int N, int E) {
    __shared__ __align__(16) float ep[32*36];

    const int t = threadIdx.x;
    const int wv = t >> 6, lane = t & 63;

    // bijective XCD swizzle (m204)
    const int nwg = gridDim.x;
    const int q = nwg >> 3, r = nwg & 7;
    const int xcd = blockIdx.x & 7, idx = blockIdx.x >> 3;
    const int logical = (xcd < r ? xcd*(q+1) : r*(q+1) + (xcd-r)*q) + idx;
    const int lt = logical >> 3;          // 32-row tile index
    const int ch = logical & 7;           // 32-col chunk (= head)
    const int m0 = lt * 32;
    const int c0 = ch * 32;
    const int cs = ch * 2;

    const int nt = lt >> 1;
    const int gbase = (lt & 1) * 2 + wv;  // 16-row quarter within the 64-row supertile

    const ushort* A0 = xpadA + ((size_t)(nt*17)*4 + gbase)*512 + lane*8;
    const ushort* B0 = BtT + (size_t)(cs + 0)*512 + lane*8;
    const ushort* B1 = BtT + (size_t)(cs + 1)*512 + lane*8;

    f32x4 acc0 = (f32x4)0.f, acc1 = (f32x4)0.f;

    short8 a[4], b0[4], b1[4];
#define LOADSET(B_, S_)                                                       \
    {                                                                         \
        a[B_]  = *reinterpret_cast<const short8*>(A0 + (size_t)(S_)*2048);    \
        b0[B_] = *reinterpret_cast<const short8*>(B0 + (size_t)(S_)*8192);    \
        b1[B_] = *reinterpret_cast<const short8*>(B1 + (size_t)(S_)*8192);    \
    }
    LOADSET(0, 0)
    LOADSET(1, 1)
    LOADSET(2, 2)
    #pragma unroll
    for (int s = 0; s < 17; ++s) {
        const int b = s & 3;
        if (s + 3 < 17) LOADSET((s + 3) & 3, s + 3)
        acc0 = __builtin_amdgcn_mfma_f32_16x16x32_bf16(a[b], b0[b], acc0, 0, 0, 0);
        acc1 = __builtin_amdgcn_mfma_f32_16x16x32_bf16(a[b], b1[b], acc1, 0, 0, 0);
    }
#undef LOADSET

    // fused CSR fill — after the K-loop (R11 lesson: vmcnt waits are oldest-first)
    {
        const int e = blockIdx.x * 128 + t;
        if (e < E) {
            const int d = dstv[e];
            const int p = atomicAdd(&cursor[d], 1);
            csr[row_start[d] + p] = src[e];
        }
    }

    // ---- epilogue: transpose through LDS; emit bf16 rows + al/ar (block = 1 head) ----
    {
        const int rq = (lane >> 4) * 4;
        const int cb = lane & 15;
        #pragma unroll
        for (int r2 = 0; r2 < 4; ++r2) {
            ep[(wv*16 + rq + r2)*36 +      cb] = acc0[r2];
            ep[(wv*16 + rq + r2)*36 + 16 + cb] = acc1[r2];
        }
    }
    __syncthreads();
    {
        const int rl = t >> 2;           // 32 rows, 4 threads/row
        const int cq = (t & 3) * 8;      // 8 cols each
        const int row = m0 + rl;
        if (row < N) {
            const float* sp = &ep[rl*36 + cq];
            float vals[8];
            #pragma unroll
            for (int i = 0; i < 8; ++i) vals[i] = sp[i];
            uint u[4];
            #pragma unroll
            for (int i = 0; i < 4; ++i)
                u[i] = (uint)f2bf(vals[2*i]) | ((uint)f2bf(vals[2*i+1]) << 16);
            *reinterpret_cast<uint4*>(&xhb[(size_t)row*256 + c0 + cq]) = make_uint4(u[0], u[1], u[2], u[3]);
            float pl = 0.f, pr = 0.f;
            #pragma unroll
            for (int i = 0; i < 8; ++i) {
                pl = fmaf(vals[i], att_l[c0 + cq + i], pl);
                pr = fmaf(vals[i], att_r[c0 + cq + i], pr);
            }
            pl += __shfl_xor(pl, 1, 64);
            pr += __shfl_xor(pr, 1, 64);
            pl += __shfl_xor(pl, 2, 64);
            pr += __shfl_xor(pr, 2, 64);
            if ((t & 3) == 0) {
                al[(size_t)row*8 + ch] = pl;
                ar[(size_t)row*8 + ch] = pr;
            }
        }
    }
}

// ---------------- per-dst single-pass softmax aggregation: 2 nodes/wave, 32 lanes/node ----------------
__global__ __launch_bounds__(256) void k_agg(
    const ushort* __restrict__ xhb,
    const float* __restrict__ al, const float* __restrict__ ar,
    const float* __restrict__ onehot, const uint* __restrict__ ohb,
    const float* __restrict__ bias,
    const int* __restrict__ row_start, const int* __restrict__ csr,
    float* __restrict__ out_x, float* __restrict__ out_oh, int N) {
    const int wave = threadIdx.x >> 6;
    const int lane = threadIdx.x & 63;
    const int half = lane >> 5;
    const int ln = lane & 31;
    const int n = blockIdx.x * 8 + wave * 2 + half;
    if (n >= N) return;
    const int h = ln >> 2;
    const float ard = ar[(size_t)n*8 + h];

    float a_self = al[(size_t)n*8 + h] + ard;
    a_self = fmaxf(a_self, NEG_SLOPE * a_self);
    float e_self = __expf(a_self);
    uint4 xsb = *reinterpret_cast<const uint4*>(&xhb[(size_t)n*256 + ln*8]);
    float acc0 = e_self * bflo(xsb.x), acc1 = e_self * bfhi(xsb.x);
    float acc2 = e_self * bflo(xsb.y), acc3 = e_self * bfhi(xsb.y);
    float acc4 = e_self * bflo(xsb.z), acc5 = e_self * bfhi(xsb.z);
    float acc6 = e_self * bflo(xsb.w), acc7 = e_self * bfhi(xsb.w);
    float den = e_self;
    float oh0 = 0.f, oh1 = 0.f, oh2 = 0.f, oh3 = 0.f;

    const int beg = row_start[n], end = row_start[n+1];
    int i = beg;
    for (; i + 1 < end; i += 2) {
        const int s0 = csr[i], s1 = csr[i+1];
        const float al0 = al[(size_t)s0*8 + h], al1 = al[(size_t)s1*8 + h];
        const uint4 x0 = *reinterpret_cast<const uint4*>(&xhb[(size_t)s0*256 + ln*8]);
        const uint4 x1 = *reinterpret_cast<const uint4*>(&xhb[(size_t)s1*256 + ln*8]);
        const uint2 o0 = *reinterpret_cast<const uint2*>(&ohb[(size_t)s0*64 + ln*2]);
        const uint2 o1 = *reinterpret_cast<const uint2*>(&ohb[(size_t)s1*64 + ln*2]);
        float a0 = al0 + ard; a0 = fmaxf(a0, NEG_SLOPE * a0);
        float a1 = al1 + ard; a1 = fmaxf(a1, NEG_SLOPE * a1);
        const float e0 = __expf(a0), e1 = __expf(a1);
        acc0 = fmaf(e0, bflo(x0.x), fmaf(e1, bflo(x1.x), acc0));
        acc1 = fmaf(e0, bfhi(x0.x), fmaf(e1, bfhi(x1.x), acc1));
        acc2 = fmaf(e0, bflo(x0.y), fmaf(e1, bflo(x1.y), acc2));
        acc3 = fmaf(e0, bfhi(x0.y), fmaf(e1, bfhi(x1.y), acc3));
        acc4 = fmaf(e0, bflo(x0.z), fmaf(e1, bflo(x1.z), acc4));
        acc5 = fmaf(e0, bfhi(x0.z), fmaf(e1, bfhi(x1.z), acc5));
        acc6 = fmaf(e0, bflo(x0.w), fmaf(e1, bflo(x1.w), acc6));
        acc7 = fmaf(e0, bfhi(x0.w), fmaf(e1, bfhi(x1.w), acc7));
        den += e0 + e1;
        oh0 += bflo(o0.x) + bflo(o1.x);
        oh1 += bfhi(o0.x) + bfhi(o1.x);
        oh2 += bflo(o0.y) + bflo(o1.y);
        oh3 += bfhi(o0.y) + bfhi(o1.y);
    }
    if (i < end) {
        const int s0 = csr[i];
        float a0 = al[(size_t)s0*8 + h] + ard;
        a0 = fmaxf(a0, NEG_SLOPE * a0);
        const float e0 = __expf(a0);
        const uint4 x0 = *reinterpret_cast<const uint4*>(&xhb[(size_t)s0*256 + ln*8]);
        const uint2 o0 = *reinterpret_cast<const uint2*>(&ohb[(size_t)s0*64 + ln*2]);
        acc0 = fmaf(e0, bflo(x0.x), acc0);
        acc1 = fmaf(e0, bfhi(x0.x), acc1);
        acc2 = fmaf(e0, bflo(x0.y), acc2);
        acc3 = fmaf(e0, bfhi(x0.y), acc3);
        acc4 = fmaf(e0, bflo(x0.z), acc4);
        acc5 = fmaf(e0, bfhi(x0.z), acc5);
        acc6 = fmaf(e0, bflo(x0.w), acc6);
        acc7 = fmaf(e0, bfhi(x0.w), acc7);
        den += e0;
        oh0 += bflo(o0.x);
        oh1 += bfhi(o0.x);
        oh2 += bflo(o0.y);
        oh3 += bfhi(o0.y);
    }
    const float inv = 1.f / den;
    const float4 bv0 = *reinterpret_cast<const float4*>(&bias[ln*8]);
    const float4 bv1 = *reinterpret_cast<const float4*>(&bias[ln*8 + 4]);
    float4 q0, q1;
    q0.x = fmaf(acc0, inv, bv0.x); q0.y = fmaf(acc1, inv, bv0.y);
    q0.z = fmaf(acc2, inv, bv0.z); q0.w = fmaf(acc3, inv, bv0.w);
    q1.x = fmaf(acc4, inv, bv1.x); q1.y = fmaf(acc5, inv, bv1.y);
    q1.z = fmaf(acc6, inv, bv1.z); q1.w = fmaf(acc7, inv, bv1.w);
    *reinterpret_cast<float4*>(&out_x[(size_t)n*256 + ln*8])     = q0;
    *reinterpret_cast<float4*>(&out_x[(size_t)n*256 + ln*8 + 4]) = q1;
    const float4 so = *reinterpret_cast<const float4*>(&onehot[(size_t)n*128 + ln*4]);
    float4 oo;
    oo.x = oh0 + 2.f*so.x;
    oo.y = oh1 + 2.f*so.y;
    oo.z = oh2 + 2.f*so.z;
    oo.w = oh3 + 2.f*so.w;
    *reinterpret_cast<float4*>(&out_oh[(size_t)n*128 + ln*4]) = oo;
}

// ---------------- launcher ----------------
extern "C" void kernel_launch(void* const* d_in, const int* in_sizes, int n_in,
                              void* d_out, int out_size, void* d_ws, size_t ws_size,
                              hipStream_t stream) {
    const float* x      = (const float*)d_in[0];
    const float* onehot = (const float*)d_in[1];
    const int*   adj    = (const int*)d_in[2];
    const float* lin_w  = (const float*)d_in[4];
    const float* att_l  = (const float*)d_in[5];
    const float* att_r  = (const float*)d_in[6];
    const float* bias   = (const float*)d_in[7];
    const float* c1w    = (const float*)d_in[8];
    const float* c1b    = (const float*)d_in[9];
    const float* c2w    = (const float*)d_in[10];
    const float* c2b    = (const float*)d_in[11];
    const float* l2w    = (const float*)d_in[12];
    const float* l2b    = (const float*)d_in[13];

    const int N = in_sizes[0] / 512;
    const int E = in_sizes[2] / 2;
    const int* src = adj;
    const int* dst = adj + E;

    float* out_x  = (float*)d_out;
    float* out_oh = out_x + (size_t)N * 256;

    const int NT = (N + 63) / 64;

    // workspace layout
    ushort* xpadA    = (ushort*)d_ws;                       // NT*17*2048 ushorts (frag-tiled)
    ushort* BtT      = xpadA + (size_t)NT * 17 * 2048;      // 17*8192 ushorts
    ushort* xhb      = BtT + (size_t)17 * 8192;             // N*256 bf16
    uint*   ohb      = (uint*)(xhb + (size_t)N * 256);      // N*64 packed bf16x2
    float*  al       = (float*)(ohb + (size_t)N * 64);      // N*8
    float*  ar       = al + (size_t)N * 8;                  // N*8
    int*   row_start = (int*)(ar + (size_t)N * 8);          // N+1
    int*   cursor    = row_start + (N + 1);                 // N
    int*   csr       = cursor + N;                          // E

    const int EB = (E + 255) / 256;
    const int NT32 = (N + 31) / 32;
    const int GB = NT32 * 8;

    k_conv_wave<<<(N + 3) / 4, 256, 0, stream>>>(x, onehot, c1w, c1b, c2w, c2b, l2w, l2b, xpadA, ohb, cursor, N);
    k_prep<<<EB, 256, 0, stream>>>(lin_w, BtT, dst, cursor, E);
    k_scan<<<1, 1024, 0, stream>>>(cursor, row_start, N);
    k_gemm_mfma<<<GB, 128, 0, stream>>>(xpadA, BtT, att_l, att_r, xhb, al, ar,
                                        src, dst, row_start, cursor, csr, N, E);
    k_agg<<<(N + 7) / 8, 256, 0, stream>>>(xhb, al, ar, onehot, ohb, bias, row_start, csr, out_x, out_oh, N);
}